// Round 9
// baseline (121.160 us; speedup 1.0000x reference)
//
#include <hip/hip_runtime.h>
#include <hip/hip_bf16.h>
#include <math.h>

// Problem constants (B,S,R,A,DW,DR) = (64,32,128,64,512,512)
#define B_  64
#define S_  32
#define R_  128
#define A_  64
#define DW_ 512
#define DR_ 512

typedef __attribute__((ext_vector_type(8))) short short8;   // 8 bf16 (4 VGPRs)
typedef __attribute__((ext_vector_type(4))) float f32x4;    // MFMA accumulator
typedef unsigned short ushort_t;

__device__ __forceinline__ ushort_t bf16_rn(float x) {
    union { float f; unsigned u; } v; v.f = x;
    unsigned r = v.u + 0x7FFF + ((v.u >> 16) & 1);
    return (ushort_t)(r >> 16);
}
__device__ __forceinline__ float bf16_to_f(ushort_t h) {
    union { unsigned u; float f; } v; v.u = ((unsigned)h) << 16;
    return v.f;
}

// Swizzled index (ushort units) within a [rows][32] bf16 tile; works for both
// 32-row (A) and 64-row (B) tiles. <=2-way bank aliasing on frag b128 reads.
__device__ __forceinline__ int swz(int row, int chunk) {
    return row * 32 + ((chunk ^ ((row >> 1) & 3)) << 3);
}

// ---------------------------------------------------------------------------
// prep: convert qv/Wq/rel/Wr fp32 -> split-bf16 (hi+lo), pre-packed per
// (row-tile, k-step) in the exact swizzled order the GEMM stages into LDS,
// so GEMM staging is a pure linear 16B copy. Tile geometry: A-operands
// (qv, rel) 32-row tiles; B-operands (Wq, Wr) 64-row tiles; K-step 32.
// pk layout per tile: [hi tile_sz ushorts][lo tile_sz ushorts].
// Grid: 800 blocks x 256 (exact; array boundaries are block-aligned).
// ---------------------------------------------------------------------------
__global__ __launch_bounds__(256) void prep_kernel(
    const float* __restrict__ qv, const float* __restrict__ Wq,
    const float* __restrict__ rel, const float* __restrict__ Wr,
    ushort_t* __restrict__ pk_qv, ushort_t* __restrict__ pk_Wq,
    ushort_t* __restrict__ pk_rel, ushort_t* __restrict__ pk_Wr)
{
    const int gid = blockIdx.x * 256 + threadIdx.x;
    const float* X; ushort_t* P; int lid, trs;
    if (gid < 131072)      { X = qv;  P = pk_qv;  lid = gid;          trs = 5; }
    else if (gid < 163840) { X = Wq;  P = pk_Wq;  lid = gid - 131072; trs = 6; }
    else if (gid < 172032) { X = rel; P = pk_rel; lid = gid - 163840; trs = 5; }
    else                   { X = Wr;  P = pk_Wr;  lid = gid - 172032; trs = 6; }

    const int row  = lid >> 6;           // K/8 = 64 groups per row
    const int c8   = lid & 63;
    const int ks   = c8 >> 2;            // k-step 0..15
    const int sch  = c8 & 3;             // 8-elem chunk within step
    const int rblk = row >> trs;
    const int srow = row & ((1 << trs) - 1);
    const int tsz  = 32 << trs;          // tile_sz ushorts (1024 or 2048)

    const float* src = X + (size_t)row * 512 + ks * 32 + sch * 8;
    float4 v0 = *(const float4*)src;
    float4 v1 = *(const float4*)(src + 4);
    float f[8] = {v0.x, v0.y, v0.z, v0.w, v1.x, v1.y, v1.z, v1.w};
    short8 hi, lo;
    #pragma unroll
    for (int e = 0; e < 8; ++e) {
        ushort_t h = bf16_rn(f[e]);
        hi[e] = (short)h;
        lo[e] = (short)bf16_rn(f[e] - bf16_to_f(h));
    }
    const size_t base = (size_t)(rblk * 16 + ks) * (size_t)(tsz * 2);
    *(short8*)&P[base + swz(srow, sch)]       = hi;
    *(short8*)&P[base + tsz + swz(srow, sch)] = lo;
}

// ---------------------------------------------------------------------------
// GEMM on pre-packed split-bf16: C[M,N] = A@B^T + biases (+ rowv*colv).
// 32x64 tile, BK=32, 256 threads = 4 waves (2x2), 6 MFMA/step/wave.
// Staging = linear 16B copies (swizzle baked into pk). Double-buffered,
// one barrier per K-step. Numerics bit-identical to validated r5-r7 GEMM.
// ---------------------------------------------------------------------------
__global__ __launch_bounds__(256) void gemm_pk_kernel(
    const ushort_t* __restrict__ pkA0, const ushort_t* __restrict__ pkB0,
    float* __restrict__ C0, int M0, int N0,
    const float* __restrict__ bias1_0, const float* __restrict__ bias2_0,
    const float* __restrict__ rowv0, const float* __restrict__ colv0,
    const ushort_t* __restrict__ pkA1, const ushort_t* __restrict__ pkB1,
    float* __restrict__ C1, int M1, int N1,
    const float* __restrict__ bias1_1)
{
    const int z = blockIdx.z;
    const ushort_t* pkA; const ushort_t* pkB; float* C;
    const float *bias1, *bias2, *rowv, *colv;
    int M, N;
    if (z == 0) {
        pkA = pkA0; pkB = pkB0; C = C0; M = M0; N = N0;
        bias1 = bias1_0; bias2 = bias2_0; rowv = rowv0; colv = colv0;
    } else {
        pkA = pkA1; pkB = pkB1; C = C1; M = M1; N = N1;
        bias1 = bias1_1; bias2 = nullptr; rowv = nullptr; colv = nullptr;
    }

    const int bm = blockIdx.x * 32;
    const int bn = blockIdx.y * 64;
    if (bm >= M || bn >= N) return;   // z==1 uses only 4 x-blocks

    __shared__ ushort_t Ab[2][2048];  // [hi 1024][lo 1024]
    __shared__ ushort_t Bb[2][4096];  // [hi 2048][lo 2048]

    const int tid = threadIdx.x;
    const int l   = tid & 63;
    const int w   = tid >> 6;
    const int wr  = w >> 1;           // wave row (0..1) -> 16 rows each
    const int wc  = w & 1;            // wave col (0..1) -> 32 cols each
    const int fr  = l & 15;
    const int fc  = l >> 4;

    f32x4 acc[2] = {};

    const size_t tA = (size_t)blockIdx.x * 16;   // A tile row-block base
    const size_t tB = (size_t)blockIdx.y * 16;

    // prologue: stage step 0 into buf 0 (pure linear copy)
    {
        const ushort_t* sA = pkA + (tA << 11);
        const ushort_t* sB = pkB + (tB << 12);
        *(short8*)&Ab[0][tid << 3]          = *(const short8*)&sA[tid << 3];
        *(short8*)&Bb[0][tid << 3]          = *(const short8*)&sB[tid << 3];
        *(short8*)&Bb[0][(tid << 3) + 2048] = *(const short8*)&sB[(tid << 3) + 2048];
    }
    __syncthreads();

    int cur = 0;
    #pragma unroll 4
    for (int s = 0; s < 16; ++s) {
        short8 la, lb0, lb1;
        if (s + 1 < 16) {             // next-step loads issue under MFMA phase
            const ushort_t* sA = pkA + ((tA + s + 1) << 11);
            const ushort_t* sB = pkB + ((tB + s + 1) << 12);
            la  = *(const short8*)&sA[tid << 3];
            lb0 = *(const short8*)&sB[tid << 3];
            lb1 = *(const short8*)&sB[(tid << 3) + 2048];
        }

        // frag reads + 6 MFMA
        const int ra = wr * 16 + fr;
        short8 ahi = *(const short8*)&Ab[cur][swz(ra, fc)];
        short8 alo = *(const short8*)&Ab[cur][1024 + swz(ra, fc)];
        #pragma unroll
        for (int j = 0; j < 2; ++j) {
            const int c = wc * 32 + j * 16 + fr;
            short8 bhi = *(const short8*)&Bb[cur][swz(c, fc)];
            short8 blo = *(const short8*)&Bb[cur][2048 + swz(c, fc)];
            acc[j] = __builtin_amdgcn_mfma_f32_16x16x32_bf16(ahi, bhi, acc[j], 0, 0, 0);
            acc[j] = __builtin_amdgcn_mfma_f32_16x16x32_bf16(ahi, blo, acc[j], 0, 0, 0);
            acc[j] = __builtin_amdgcn_mfma_f32_16x16x32_bf16(alo, bhi, acc[j], 0, 0, 0);
        }

        if (s + 1 < 16) {
            const int nxt = cur ^ 1;
            *(short8*)&Ab[nxt][tid << 3]          = la;
            *(short8*)&Bb[nxt][tid << 3]          = lb0;
            *(short8*)&Bb[nxt][(tid << 3) + 2048] = lb1;
            __syncthreads();
            cur = nxt;
        }
    }

    // Epilogue. C/D layout (m89): col = l&15, row = (l>>4)*4 + reg.
    #pragma unroll
    for (int j = 0; j < 2; ++j) {
        const int n  = bn + wc * 32 + j * 16 + fr;
        const float b1 = bias1[n];
        const float b2 = bias2 ? bias2[n] : 0.0f;
        const float cv = colv ? colv[n] : 0.0f;
        #pragma unroll
        for (int reg = 0; reg < 4; ++reg) {
            const int m = bm + wr * 16 + fc * 4 + reg;
            float v = acc[j][reg] + b1 + b2;
            if (rowv) v += rowv[m] * cv;
            C[(size_t)m * N + n] = v;
        }
    }
}

// One block per (b, group of 8 a's). Folded-tanh identity (byte-identical to
// validated r7 kernel):
//   sum_d wa_d*tanh(u_d+rp_d) = sum_d wa_d - 2*sum_d wa_d/(exp2(K2*u_d+rp2_d)+1)
__global__ __launch_bounds__(256) void attn_kernel(
    const float* __restrict__ u,      // [B*S, DR]
    const float* __restrict__ rp,     // [R, DR]
    const float* __restrict__ watt,   // [DR]
    const float* __restrict__ battp,  // [1]
    const float* __restrict__ qv,     // [B*S, DW]
    const unsigned char* __restrict__ mask, // [B*S]
    const int* __restrict__ rspace,   // [B*A]
    float* __restrict__ out,          // [B*A, DW]
    float* __restrict__ alpha_out)    // [B*A, S]
{
    const int blk  = blockIdx.x;      // b*8 + grp
    const int b    = blk >> 3;
    const int ba0  = b * A_ + ((blk & 7) << 3);
    const int tid  = threadIdx.x;
    const int lane = tid & 63;
    const int wave = tid >> 6;

    const float K2 = 2.8853900817779268f;  // 2*log2(e)

    __shared__ float s_scores[8][S_];
    __shared__ float s_alpha[8][S_];

    float wav[8], rp2[8][8];
    {
        const float4* wa4 = (const float4*)watt;
        #pragma unroll
        for (int v = 0; v < 2; ++v) {
            float4 w = wa4[v * 64 + lane];
            wav[v*4+0] = w.x; wav[v*4+1] = w.y; wav[v*4+2] = w.z; wav[v*4+3] = w.w;
        }
        #pragma unroll
        for (int g = 0; g < 8; ++g) {
            const float4* rp4 = (const float4*)(rp + (size_t)rspace[ba0 + g] * DR_);
            #pragma unroll
            for (int v = 0; v < 2; ++v) {
                float4 t = rp4[v * 64 + lane];
                rp2[g][v*4+0] = t.x * K2; rp2[g][v*4+1] = t.y * K2;
                rp2[g][v*4+2] = t.z * K2; rp2[g][v*4+3] = t.w * K2;
            }
        }
    }
    const float batt = battp[0];

    float swa = wav[0] + wav[1] + wav[2] + wav[3] + wav[4] + wav[5] + wav[6] + wav[7];
    #pragma unroll
    for (int off = 32; off > 0; off >>= 1)
        swa += __shfl_xor(swa, off);

    #pragma unroll
    for (int si = 0; si < 8; ++si) {
        const int s = (wave << 3) + si;
        const float4* u4 = (const float4*)(u + ((size_t)b * S_ + s) * DR_);
        float uu[8];
        #pragma unroll
        for (int v = 0; v < 2; ++v) {
            float4 t = u4[v * 64 + lane];
            uu[v*4+0] = t.x; uu[v*4+1] = t.y; uu[v*4+2] = t.z; uu[v*4+3] = t.w;
        }
        float ac[8] = {};
        #pragma unroll
        for (int e = 0; e < 8; ++e) {
            const float we = wav[e];
            const float uk = uu[e] * K2;
            #pragma unroll
            for (int g = 0; g < 8; ++g) {
                float zz = __builtin_amdgcn_exp2f(uk + rp2[g][e]);
                ac[g] = fmaf(we, __builtin_amdgcn_rcpf(zz + 1.0f), ac[g]);
            }
        }
        #pragma unroll
        for (int off = 32; off > 0; off >>= 1)
            #pragma unroll
            for (int g = 0; g < 8; ++g)
                ac[g] += __shfl_xor(ac[g], off);
        if (lane == 0)
            #pragma unroll
            for (int g = 0; g < 8; ++g)
                s_scores[g][s] = fmaf(-2.0f, ac[g], swa) + batt;
    }
    __syncthreads();

    {
        const int g = tid >> 5;
        const int s = tid & 31;
        float sc = s_scores[g][s];
        if (mask[b * S_ + s]) sc = -INFINITY;
        float m = sc;
        #pragma unroll
        for (int off = 16; off > 0; off >>= 1)
            m = fmaxf(m, __shfl_xor(m, off));
        float e = __expf(sc - m);
        float sum = e;
        #pragma unroll
        for (int off = 16; off > 0; off >>= 1)
            sum += __shfl_xor(sum, off);
        float al = e / sum;
        s_alpha[g][s] = al;
        alpha_out[(size_t)(ba0 + g) * S_ + s] = al;
    }
    __syncthreads();

    float2 acc2[8] = {};
    const float* qb = qv + (size_t)b * S_ * DW_;
    #pragma unroll 4
    for (int s = 0; s < S_; ++s) {
        float2 q = *(const float2*)&qb[s * DW_ + tid * 2];
        #pragma unroll
        for (int g = 0; g < 8; ++g) {
            const float al = s_alpha[g][s];
            acc2[g].x = fmaf(al, q.x, acc2[g].x);
            acc2[g].y = fmaf(al, q.y, acc2[g].y);
        }
    }
    #pragma unroll
    for (int g = 0; g < 8; ++g)
        *(float2*)&out[(size_t)(ba0 + g) * DW_ + tid * 2] = acc2[g];
}

extern "C" void kernel_launch(void* const* d_in, const int* in_sizes, int n_in,
                              void* d_out, int out_size, void* d_ws, size_t ws_size,
                              hipStream_t stream) {
    const float*         qv   = (const float*)d_in[0];          // [B,S,DW]
    const unsigned char* mask = (const unsigned char*)d_in[1];  // [B,S] bool
    const int*           rsp  = (const int*)d_in[2];            // [B,A]
    const float*         cov  = (const float*)d_in[3];          // [B,S]
    const float*         rel  = (const float*)d_in[4];          // [R,DR]
    const float*         Wq   = (const float*)d_in[5];          // [DR,DW]
    const float*         bq   = (const float*)d_in[6];          // [DR]
    const float*         Wr   = (const float*)d_in[7];          // [DR,DR]
    const float*         br   = (const float*)d_in[8];          // [DR]
    const float*         Wc   = (const float*)d_in[9];          // [DR,1] -> [DR]
    const float*         bc   = (const float*)d_in[10];         // [DR]
    const float*         Watt = (const float*)d_in[11];         // [1,DR] -> [DR]
    const float*         batt = (const float*)d_in[12];         // [1]

    // ws layout: u [2048x512 f32] | rp [128x512 f32] | pk arrays (ushort)
    float*    u      = (float*)d_ws;
    float*    rp     = u + (size_t)B_ * S_ * DR_;
    ushort_t* pk     = (ushort_t*)(rp + (size_t)R_ * DR_);
    ushort_t* pk_qv  = pk;                      // 2048*512*2 ushorts
    ushort_t* pk_Wq  = pk_qv  + 2097152;        //  512*512*2
    ushort_t* pk_rel = pk_Wq  + 524288;         //  128*512*2
    ushort_t* pk_Wr  = pk_rel + 131072;         //  512*512*2

    float* out       = (float*)d_out;                 // [B,A,DW]
    float* alpha_out = out + (size_t)B_ * A_ * DW_;   // [B,A,S]

    dim3 blk(256);

    prep_kernel<<<dim3(800), blk, 0, stream>>>(
        qv, Wq, rel, Wr, pk_qv, pk_Wq, pk_rel, pk_Wr);

    gemm_pk_kernel<<<dim3(64, 8, 2), blk, 0, stream>>>(
        pk_qv, pk_Wq, u, B_ * S_, DR_, bq, bc, cov, Wc,
        pk_rel, pk_Wr, rp, R_, DR_, br);

    attn_kernel<<<dim3(B_ * (A_ / 8)), blk, 0, stream>>>(
        u, rp, Watt, batt, qv, mask, rsp, out, alpha_out);
}

// Round 10
// 118.778 us; speedup vs baseline: 1.0200x; 1.0200x over previous
//
#include <hip/hip_runtime.h>
#include <hip/hip_bf16.h>
#include <math.h>

// Problem constants (B,S,R,A,DW,DR) = (64,32,128,64,512,512)
#define B_  64
#define S_  32
#define R_  128
#define A_  64
#define DW_ 512
#define DR_ 512

typedef __attribute__((ext_vector_type(8))) short short8;   // 8 bf16 (4 VGPRs)
typedef __attribute__((ext_vector_type(4))) float f32x4;    // MFMA accumulator
typedef unsigned short ushort_t;

__device__ __forceinline__ ushort_t bf16_rn(float x) {
    union { float f; unsigned u; } v; v.f = x;
    unsigned r = v.u + 0x7FFF + ((v.u >> 16) & 1);
    return (ushort_t)(r >> 16);
}
__device__ __forceinline__ float bf16_to_f(ushort_t h) {
    union { unsigned u; float f; } v; v.u = ((unsigned)h) << 16;
    return v.f;
}

// Swizzled index (ushort units) within a [rows][32] bf16 tile.
__device__ __forceinline__ int swz(int row, int chunk) {
    return row * 32 + ((chunk ^ ((row >> 1) & 3)) << 3);
}

// ---------------------------------------------------------------------------
// prep: fp32 -> split-bf16 (hi+lo), pre-packed in GEMM LDS staging order.
// Byte-identical to validated r9 kernel.
// ---------------------------------------------------------------------------
__global__ __launch_bounds__(256) void prep_kernel(
    const float* __restrict__ qv, const float* __restrict__ Wq,
    const float* __restrict__ rel, const float* __restrict__ Wr,
    ushort_t* __restrict__ pk_qv, ushort_t* __restrict__ pk_Wq,
    ushort_t* __restrict__ pk_rel, ushort_t* __restrict__ pk_Wr)
{
    const int gid = blockIdx.x * 256 + threadIdx.x;
    const float* X; ushort_t* P; int lid, trs;
    if (gid < 131072)      { X = qv;  P = pk_qv;  lid = gid;          trs = 5; }
    else if (gid < 163840) { X = Wq;  P = pk_Wq;  lid = gid - 131072; trs = 6; }
    else if (gid < 172032) { X = rel; P = pk_rel; lid = gid - 163840; trs = 5; }
    else                   { X = Wr;  P = pk_Wr;  lid = gid - 172032; trs = 6; }

    const int row  = lid >> 6;
    const int c8   = lid & 63;
    const int ks   = c8 >> 2;
    const int sch  = c8 & 3;
    const int rblk = row >> trs;
    const int srow = row & ((1 << trs) - 1);
    const int tsz  = 32 << trs;

    const float* src = X + (size_t)row * 512 + ks * 32 + sch * 8;
    float4 v0 = *(const float4*)src;
    float4 v1 = *(const float4*)(src + 4);
    float f[8] = {v0.x, v0.y, v0.z, v0.w, v1.x, v1.y, v1.z, v1.w};
    short8 hi, lo;
    #pragma unroll
    for (int e = 0; e < 8; ++e) {
        ushort_t h = bf16_rn(f[e]);
        hi[e] = (short)h;
        lo[e] = (short)bf16_rn(f[e] - bf16_to_f(h));
    }
    const size_t base = (size_t)(rblk * 16 + ks) * (size_t)(tsz * 2);
    *(short8*)&P[base + swz(srow, sch)]       = hi;
    *(short8*)&P[base + tsz + swz(srow, sch)] = lo;
}

// ---------------------------------------------------------------------------
// GEMM on pre-packed split-bf16. Byte-identical to validated r9 kernel.
// ---------------------------------------------------------------------------
__global__ __launch_bounds__(256) void gemm_pk_kernel(
    const ushort_t* __restrict__ pkA0, const ushort_t* __restrict__ pkB0,
    float* __restrict__ C0, int M0, int N0,
    const float* __restrict__ bias1_0, const float* __restrict__ bias2_0,
    const float* __restrict__ rowv0, const float* __restrict__ colv0,
    const ushort_t* __restrict__ pkA1, const ushort_t* __restrict__ pkB1,
    float* __restrict__ C1, int M1, int N1,
    const float* __restrict__ bias1_1)
{
    const int z = blockIdx.z;
    const ushort_t* pkA; const ushort_t* pkB; float* C;
    const float *bias1, *bias2, *rowv, *colv;
    int M, N;
    if (z == 0) {
        pkA = pkA0; pkB = pkB0; C = C0; M = M0; N = N0;
        bias1 = bias1_0; bias2 = bias2_0; rowv = rowv0; colv = colv0;
    } else {
        pkA = pkA1; pkB = pkB1; C = C1; M = M1; N = N1;
        bias1 = bias1_1; bias2 = nullptr; rowv = nullptr; colv = nullptr;
    }

    const int bm = blockIdx.x * 32;
    const int bn = blockIdx.y * 64;
    if (bm >= M || bn >= N) return;

    __shared__ ushort_t Ab[2][2048];
    __shared__ ushort_t Bb[2][4096];

    const int tid = threadIdx.x;
    const int l   = tid & 63;
    const int w   = tid >> 6;
    const int wr  = w >> 1;
    const int wc  = w & 1;
    const int fr  = l & 15;
    const int fc  = l >> 4;

    f32x4 acc[2] = {};

    const size_t tA = (size_t)blockIdx.x * 16;
    const size_t tB = (size_t)blockIdx.y * 16;

    {
        const ushort_t* sA = pkA + (tA << 11);
        const ushort_t* sB = pkB + (tB << 12);
        *(short8*)&Ab[0][tid << 3]          = *(const short8*)&sA[tid << 3];
        *(short8*)&Bb[0][tid << 3]          = *(const short8*)&sB[tid << 3];
        *(short8*)&Bb[0][(tid << 3) + 2048] = *(const short8*)&sB[(tid << 3) + 2048];
    }
    __syncthreads();

    int cur = 0;
    #pragma unroll 4
    for (int s = 0; s < 16; ++s) {
        short8 la, lb0, lb1;
        if (s + 1 < 16) {
            const ushort_t* sA = pkA + ((tA + s + 1) << 11);
            const ushort_t* sB = pkB + ((tB + s + 1) << 12);
            la  = *(const short8*)&sA[tid << 3];
            lb0 = *(const short8*)&sB[tid << 3];
            lb1 = *(const short8*)&sB[(tid << 3) + 2048];
        }

        const int ra = wr * 16 + fr;
        short8 ahi = *(const short8*)&Ab[cur][swz(ra, fc)];
        short8 alo = *(const short8*)&Ab[cur][1024 + swz(ra, fc)];
        #pragma unroll
        for (int j = 0; j < 2; ++j) {
            const int c = wc * 32 + j * 16 + fr;
            short8 bhi = *(const short8*)&Bb[cur][swz(c, fc)];
            short8 blo = *(const short8*)&Bb[cur][2048 + swz(c, fc)];
            acc[j] = __builtin_amdgcn_mfma_f32_16x16x32_bf16(ahi, bhi, acc[j], 0, 0, 0);
            acc[j] = __builtin_amdgcn_mfma_f32_16x16x32_bf16(ahi, blo, acc[j], 0, 0, 0);
            acc[j] = __builtin_amdgcn_mfma_f32_16x16x32_bf16(alo, bhi, acc[j], 0, 0, 0);
        }

        if (s + 1 < 16) {
            const int nxt = cur ^ 1;
            *(short8*)&Ab[nxt][tid << 3]          = la;
            *(short8*)&Bb[nxt][tid << 3]          = lb0;
            *(short8*)&Bb[nxt][(tid << 3) + 2048] = lb1;
            __syncthreads();
            cur = nxt;
        }
    }

    #pragma unroll
    for (int j = 0; j < 2; ++j) {
        const int n  = bn + wc * 32 + j * 16 + fr;
        const float b1 = bias1[n];
        const float b2 = bias2 ? bias2[n] : 0.0f;
        const float cv = colv ? colv[n] : 0.0f;
        #pragma unroll
        for (int reg = 0; reg < 4; ++reg) {
            const int m = bm + wr * 16 + fc * 4 + reg;
            float v = acc[j][reg] + b1 + b2;
            if (rowv) v += rowv[m] * cv;
            C[(size_t)m * N + n] = v;
        }
    }
}

// One block per (grp, b) with TRANSPOSED mapping: blk = grp*64 + b, G=4 a's
// per block. Since 64 % 8 == 0, all 16 groups of batch b land on XCD b%8 ->
// b's u/qv slices are HBM-fetched once and L2-served thereafter (r9: the
// b-major mapping spread each b across all 8 XCD L2s -> 34 MB HBM re-fetch,
// 20% occupancy, latency-bound). 1024 blocks = 4/CU. Score math identical
// order to r5-r9 -> bit-identical outputs.
__global__ __launch_bounds__(256) void attn_kernel(
    const float* __restrict__ u,      // [B*S, DR]
    const float* __restrict__ rp,     // [R, DR]
    const float* __restrict__ watt,   // [DR]
    const float* __restrict__ battp,  // [1]
    const float* __restrict__ qv,     // [B*S, DW]
    const unsigned char* __restrict__ mask, // [B*S]
    const int* __restrict__ rspace,   // [B*A]
    float* __restrict__ out,          // [B*A, DW]
    float* __restrict__ alpha_out)    // [B*A, S]
{
    const int blk  = blockIdx.x;      // grp*64 + b  (transposed)
    const int b    = blk & 63;
    const int grp  = blk >> 6;        // 0..15
    const int ba0  = b * A_ + (grp << 2);  // first of 4 consecutive a's
    const int tid  = threadIdx.x;
    const int lane = tid & 63;
    const int wave = tid >> 6;

    const float K2 = 2.8853900817779268f;  // 2*log2(e)

    __shared__ float s_scores[4][S_];
    __shared__ float s_alpha[4][S_];

    float wav[8], rp2[4][8];
    {
        const float4* wa4 = (const float4*)watt;
        #pragma unroll
        for (int v = 0; v < 2; ++v) {
            float4 w = wa4[v * 64 + lane];
            wav[v*4+0] = w.x; wav[v*4+1] = w.y; wav[v*4+2] = w.z; wav[v*4+3] = w.w;
        }
        #pragma unroll
        for (int g = 0; g < 4; ++g) {
            const float4* rp4 = (const float4*)(rp + (size_t)rspace[ba0 + g] * DR_);
            #pragma unroll
            for (int v = 0; v < 2; ++v) {
                float4 t = rp4[v * 64 + lane];
                rp2[g][v*4+0] = t.x * K2; rp2[g][v*4+1] = t.y * K2;
                rp2[g][v*4+2] = t.z * K2; rp2[g][v*4+3] = t.w * K2;
            }
        }
    }
    const float batt = battp[0];

    float swa = wav[0] + wav[1] + wav[2] + wav[3] + wav[4] + wav[5] + wav[6] + wav[7];
    #pragma unroll
    for (int off = 32; off > 0; off >>= 1)
        swa += __shfl_xor(swa, off);

    #pragma unroll
    for (int si = 0; si < 8; ++si) {
        const int s = (wave << 3) + si;
        const float4* u4 = (const float4*)(u + ((size_t)b * S_ + s) * DR_);
        float uu[8];
        #pragma unroll
        for (int v = 0; v < 2; ++v) {
            float4 t = u4[v * 64 + lane];
            uu[v*4+0] = t.x; uu[v*4+1] = t.y; uu[v*4+2] = t.z; uu[v*4+3] = t.w;
        }
        float ac[4] = {};
        #pragma unroll
        for (int e = 0; e < 8; ++e) {
            const float we = wav[e];
            const float uk = uu[e] * K2;
            #pragma unroll
            for (int g = 0; g < 4; ++g) {
                float zz = __builtin_amdgcn_exp2f(uk + rp2[g][e]);
                ac[g] = fmaf(we, __builtin_amdgcn_rcpf(zz + 1.0f), ac[g]);
            }
        }
        #pragma unroll
        for (int off = 32; off > 0; off >>= 1)
            #pragma unroll
            for (int g = 0; g < 4; ++g)
                ac[g] += __shfl_xor(ac[g], off);
        if (lane == 0)
            #pragma unroll
            for (int g = 0; g < 4; ++g)
                s_scores[g][s] = fmaf(-2.0f, ac[g], swa) + batt;
    }
    __syncthreads();

    if (tid < 128) {
        const int g = tid >> 5;
        const int s = tid & 31;
        float sc = s_scores[g][s];
        if (mask[b * S_ + s]) sc = -INFINITY;
        float m = sc;
        #pragma unroll
        for (int off = 16; off > 0; off >>= 1)
            m = fmaxf(m, __shfl_xor(m, off));
        float e = __expf(sc - m);
        float sum = e;
        #pragma unroll
        for (int off = 16; off > 0; off >>= 1)
            sum += __shfl_xor(sum, off);
        float al = e / sum;
        s_alpha[g][s] = al;
        alpha_out[(size_t)(ba0 + g) * S_ + s] = al;
    }
    __syncthreads();

    float2 acc2[4] = {};
    const float* qb = qv + (size_t)b * S_ * DW_;
    #pragma unroll 4
    for (int s = 0; s < S_; ++s) {
        float2 q = *(const float2*)&qb[s * DW_ + tid * 2];
        #pragma unroll
        for (int g = 0; g < 4; ++g) {
            const float al = s_alpha[g][s];
            acc2[g].x = fmaf(al, q.x, acc2[g].x);
            acc2[g].y = fmaf(al, q.y, acc2[g].y);
        }
    }
    #pragma unroll
    for (int g = 0; g < 4; ++g)
        *(float2*)&out[(size_t)(ba0 + g) * DW_ + tid * 2] = acc2[g];
}

extern "C" void kernel_launch(void* const* d_in, const int* in_sizes, int n_in,
                              void* d_out, int out_size, void* d_ws, size_t ws_size,
                              hipStream_t stream) {
    const float*         qv   = (const float*)d_in[0];          // [B,S,DW]
    const unsigned char* mask = (const unsigned char*)d_in[1];  // [B,S] bool
    const int*           rsp  = (const int*)d_in[2];            // [B,A]
    const float*         cov  = (const float*)d_in[3];          // [B,S]
    const float*         rel  = (const float*)d_in[4];          // [R,DR]
    const float*         Wq   = (const float*)d_in[5];          // [DR,DW]
    const float*         bq   = (const float*)d_in[6];          // [DR]
    const float*         Wr   = (const float*)d_in[7];          // [DR,DR]
    const float*         br   = (const float*)d_in[8];          // [DR]
    const float*         Wc   = (const float*)d_in[9];          // [DR,1] -> [DR]
    const float*         bc   = (const float*)d_in[10];         // [DR]
    const float*         Watt = (const float*)d_in[11];         // [1,DR] -> [DR]
    const float*         batt = (const float*)d_in[12];         // [1]

    // ws layout: u [2048x512 f32] | rp [128x512 f32] | pk arrays (ushort)
    float*    u      = (float*)d_ws;
    float*    rp     = u + (size_t)B_ * S_ * DR_;
    ushort_t* pk     = (ushort_t*)(rp + (size_t)R_ * DR_);
    ushort_t* pk_qv  = pk;                      // 2048*512*2 ushorts
    ushort_t* pk_Wq  = pk_qv  + 2097152;        //  512*512*2
    ushort_t* pk_rel = pk_Wq  + 524288;         //  128*512*2
    ushort_t* pk_Wr  = pk_rel + 131072;         //  512*512*2

    float* out       = (float*)d_out;                 // [B,A,DW]
    float* alpha_out = out + (size_t)B_ * A_ * DW_;   // [B,A,S]

    dim3 blk(256);

    prep_kernel<<<dim3(800), blk, 0, stream>>>(
        qv, Wq, rel, Wr, pk_qv, pk_Wq, pk_rel, pk_Wr);

    gemm_pk_kernel<<<dim3(64, 8, 2), blk, 0, stream>>>(
        pk_qv, pk_Wq, u, B_ * S_, DR_, bq, bc, cov, Wc,
        pk_rel, pk_Wr, rp, R_, DR_, br);

    attn_kernel<<<dim3(B_ * (A_ / 4)), blk, 0, stream>>>(
        u, rp, Watt, batt, qv, mask, rsp, out, alpha_out);
}